// Round 1
// baseline (27.847 us; speedup 1.0000x reference)
//
#include <hip/hip_runtime.h>

#define NCLS     256
#define DIM      1024
#define HPW      32          // patches per side (512/16)
#define PATCHSZ  16
#define IMG      512
#define PPB      8           // patches per block
#define NTHREADS 512
#define DPT      (DIM / NTHREADS)   // dims per thread = 2
#define NWAVES   (NTHREADS / 64)

__global__ __launch_bounds__(NTHREADS)
void semtok_kernel(const int* __restrict__ smap,
                   const float* __restrict__ table,
                   const float* __restrict__ gamma,
                   const float* __restrict__ beta,
                   float* __restrict__ out)
{
    __shared__ unsigned int cnt[PPB * NCLS];       // 8 KB: counts, then f32 bits
    __shared__ float red[NWAVES][PPB][2];          // cross-wave LN reduction

    const int t   = threadIdx.x;
    const int pw0 = blockIdx.x * PPB;              // first patch-col of this block
    const int ph  = blockIdx.y;                    // patch-row
    const int b   = blockIdx.z;                    // batch

    // ---- phase 1: zero + histogram ----------------------------------------
    #pragma unroll
    for (int i = t; i < PPB * NCLS; i += NTHREADS) cnt[i] = 0u;
    __syncthreads();

    // block region: rows ph*16 .. +16, cols pw0*16 .. +128  (2048 px, 512 int4)
    const int* base = smap + ((size_t)b * IMG + (size_t)ph * PATCHSZ) * IMG
                           + (size_t)pw0 * PATCHSZ;
    {
        const int pix = t * 4;                     // 0..2044
        const int row = pix >> 7;                  // / 128
        const int col = pix & 127;
        const int4 q = *reinterpret_cast<const int4*>(base + (size_t)row * IMG + col);
        unsigned int* hp = &cnt[(col >> 4) * NCLS];
        atomicAdd(&hp[min(max(q.x, 0), NCLS - 1)], 1u);
        atomicAdd(&hp[min(max(q.y, 0), NCLS - 1)], 1u);
        atomicAdd(&hp[min(max(q.z, 0), NCLS - 1)], 1u);
        atomicAdd(&hp[min(max(q.w, 0), NCLS - 1)], 1u);
    }
    __syncthreads();

    // ---- phase 2: counts -> f32 * (1/256), stored as bits in place --------
    #pragma unroll
    for (int i = t; i < PPB * NCLS; i += NTHREADS) {
        const float f = (float)cnt[i] * (1.0f / 256.0f);
        cnt[i] = __float_as_uint(f);
    }
    __syncthreads();

    // ---- phase 3: pooled = (counts/256) @ table ----------------------------
    const int d0 = t * DPT;                        // this thread's 2 dims
    float acc[PPB][DPT];
    #pragma unroll
    for (int p = 0; p < PPB; ++p) { acc[p][0] = 0.f; acc[p][1] = 0.f; }

    const float* tp = table + d0;
    #pragma unroll 2
    for (int c4 = 0; c4 < NCLS; c4 += 4) {
        const float2 tv0 = *reinterpret_cast<const float2*>(tp + (size_t)(c4 + 0) * DIM);
        const float2 tv1 = *reinterpret_cast<const float2*>(tp + (size_t)(c4 + 1) * DIM);
        const float2 tv2 = *reinterpret_cast<const float2*>(tp + (size_t)(c4 + 2) * DIM);
        const float2 tv3 = *reinterpret_cast<const float2*>(tp + (size_t)(c4 + 3) * DIM);
        #pragma unroll
        for (int p = 0; p < PPB; ++p) {
            const float4 cc = *reinterpret_cast<const float4*>(&cnt[p * NCLS + c4]); // LDS broadcast
            acc[p][0] += cc.x * tv0.x;  acc[p][1] += cc.x * tv0.y;
            acc[p][0] += cc.y * tv1.x;  acc[p][1] += cc.y * tv1.y;
            acc[p][0] += cc.z * tv2.x;  acc[p][1] += cc.z * tv2.y;
            acc[p][0] += cc.w * tv3.x;  acc[p][1] += cc.w * tv3.y;
        }
    }

    // ---- phase 4: sincos positional embedding ------------------------------
    // pos[ph,pw,d]: d<256: sin(ph*w_k); d<512: cos(ph*w_k); d<768: sin(pw*w_k);
    // else cos(pw*w_k), where k = d & 255, w_k = 10000^(-k/256).
    #pragma unroll
    for (int j = 0; j < DPT; ++j) {
        const int dj   = d0 + j;
        const int quad = dj >> 8;
        const int k    = dj & 255;
        const float omega = exp2f(-(float)k * (13.287712379549449f / 256.0f)); // log2(10000)
        if (quad < 2) {
            float sv, cv;
            __sincosf((float)ph * omega, &sv, &cv);
            const float v = (quad & 1) ? cv : sv;
            #pragma unroll
            for (int p = 0; p < PPB; ++p) acc[p][j] += v;
        } else {
            #pragma unroll
            for (int p = 0; p < PPB; ++p) {
                float sv, cv;
                __sincosf((float)(pw0 + p) * omega, &sv, &cv);
                acc[p][j] += (quad & 1) ? cv : sv;
            }
        }
    }

    // ---- phase 5: LayerNorm over DIM across the block ----------------------
    float s[PPB], s2[PPB];
    #pragma unroll
    for (int p = 0; p < PPB; ++p) {
        s[p]  = acc[p][0] + acc[p][1];
        s2[p] = acc[p][0] * acc[p][0] + acc[p][1] * acc[p][1];
    }
    #pragma unroll
    for (int off = 32; off > 0; off >>= 1) {
        #pragma unroll
        for (int p = 0; p < PPB; ++p) {
            s[p]  += __shfl_xor(s[p],  off, 64);
            s2[p] += __shfl_xor(s2[p], off, 64);
        }
    }
    const int wid  = t >> 6;
    const int lane = t & 63;
    if (lane == 0) {
        #pragma unroll
        for (int p = 0; p < PPB; ++p) { red[wid][p][0] = s[p]; red[wid][p][1] = s2[p]; }
    }
    __syncthreads();

    const float2 g  = *reinterpret_cast<const float2*>(gamma + d0);
    const float2 bt = *reinterpret_cast<const float2*>(beta  + d0);

    #pragma unroll
    for (int p = 0; p < PPB; ++p) {
        float S = 0.f, S2 = 0.f;
        #pragma unroll
        for (int w = 0; w < NWAVES; ++w) { S += red[w][p][0]; S2 += red[w][p][1]; }
        const float mu   = S * (1.0f / DIM);
        const float var  = S2 * (1.0f / DIM) - mu * mu;
        const float rstd = rsqrtf(var + 1e-5f);
        const int token  = ph * HPW + pw0 + p;
        float2 o;
        o.x = (acc[p][0] - mu) * rstd * g.x + bt.x;
        o.y = (acc[p][1] - mu) * rstd * g.y + bt.y;
        *reinterpret_cast<float2*>(out + ((size_t)b * (HPW * HPW) + token) * DIM + d0) = o;
    }
}

extern "C" void kernel_launch(void* const* d_in, const int* in_sizes, int n_in,
                              void* d_out, int out_size, void* d_ws, size_t ws_size,
                              hipStream_t stream) {
    const int*   smap  = (const int*)d_in[0];
    const float* table = (const float*)d_in[1];
    const float* gamma = (const float*)d_in[2];
    const float* beta  = (const float*)d_in[3];
    float*       out   = (float*)d_out;

    const int batches = in_sizes[0] / (IMG * IMG);   // = 2
    dim3 grid(HPW / PPB, HPW, batches);              // (4, 32, 2)
    semtok_kernel<<<grid, NTHREADS, 0, stream>>>(smap, table, gamma, beta, out);
}